// Round 7
// baseline (218.776 us; speedup 1.0000x reference)
//
#include <hip/hip_runtime.h>
#include <hip/hip_bf16.h>
#include <math.h>

// Problem constants
#define NB    8          // batch
#define CIN   512        // in channels
#define HW    3136       // 56*56
#define CH    128        // attention channels
#define TCH   384        // 3*CH
#define SCALE 0.08838834764831845f   // 128^-0.5
#define QKSCALE 0.12751744f          // SCALE * log2(e), folded into Q at proj time
#define BNEPS 1e-5f
#define NSPLIT 4         // KV splits (49 tiles of 64 -> 13/12/12/12)

typedef __attribute__((ext_vector_type(8)))  short bf16x8;
typedef __attribute__((ext_vector_type(4)))  short bf16x4;
typedef __attribute__((ext_vector_type(4)))  float f32x4;
typedef __attribute__((ext_vector_type(16))) float f32x16;

#define MFMA16(a, b, c) __builtin_amdgcn_mfma_f32_16x16x32_bf16((a), (b), (c), 0, 0, 0)
#define MFMA32(a, b, c) __builtin_amdgcn_mfma_f32_32x32x16_bf16((a), (b), (c), 0, 0, 0)

__device__ inline short f2bf(float f) {
    __hip_bfloat16 h = __float2bfloat16(f);
    return *reinterpret_cast<short*>(&h);
}
__device__ inline unsigned pack2bf(float a, float b) {
    return (unsigned)(unsigned short)f2bf(a) | ((unsigned)(unsigned short)f2bf(b) << 16);
}
__device__ inline float bfraw2f(unsigned short u) {
    return __uint_as_float(((unsigned)u) << 16);
}
__device__ inline float exp2a(float x) {           // raw v_exp_f32 (2^x)
    float r; asm("v_exp_f32 %0, %1" : "=v"(r) : "v"(x)); return r;
}

// ---------------------------------------------------------------------------
// Kernel 0a: convert Ww and Zw f32 -> bf16.
// ---------------------------------------------------------------------------
__global__ __launch_bounds__(256) void cvt_wts(const float* __restrict__ Ww,
                                               const float* __restrict__ Zw,
                                               __hip_bfloat16* __restrict__ WwB,
                                               __hip_bfloat16* __restrict__ ZwB) {
    const int nW = TCH * CIN / 4;
    const int nZ = CIN * CH / 4;
    int i = blockIdx.x * 256 + threadIdx.x;
    if (i < nW) {
        float4 v = ((const float4*)Ww)[i];
        bf16x4 o; o[0] = f2bf(v.x); o[1] = f2bf(v.y); o[2] = f2bf(v.z); o[3] = f2bf(v.w);
        ((bf16x4*)WwB)[i] = o;
    } else if (i < nW + nZ) {
        int j = i - nW;
        float4 v = ((const float4*)Zw)[j];
        bf16x4 o; o[0] = f2bf(v.x); o[1] = f2bf(v.y); o[2] = f2bf(v.z); o[3] = f2bf(v.w);
        ((bf16x4*)ZwB)[j] = o;
    }
}

// ---------------------------------------------------------------------------
// Kernel 0b: xT[n][q][c] bf16 = transpose+cvt of x[n][c][q] f32. (unchanged)
// ---------------------------------------------------------------------------
__global__ __launch_bounds__(256) void xpose_kernel(const float* __restrict__ x,
                                                    __hip_bfloat16* __restrict__ xT) {
    const int n = blockIdx.z, c0 = blockIdx.y * 64, q0 = blockIdx.x * 64;
    const int tid = threadIdx.x;
    const int mr = tid >> 4, mq = tid & 15;

    __shared__ char T[64 * 128];

    const float* xp = x + ((size_t)(n * CIN + c0 + mr * 4)) * HW + q0 + mq * 4;
    float4 r0 = *(const float4*)(xp);
    float4 r1 = *(const float4*)(xp + HW);
    float4 r2 = *(const float4*)(xp + 2 * HW);
    float4 r3 = *(const float4*)(xp + 3 * HW);
    const float* f0 = (const float*)&r0; const float* f1 = (const float*)&r1;
    const float* f2 = (const float*)&r2; const float* f3 = (const float*)&r3;
#pragma unroll
    for (int j = 0; j < 4; ++j) {
        int q = mq * 4 + j;
        bf16x4 v; v[0] = f2bf(f0[j]); v[1] = f2bf(f1[j]);
                  v[2] = f2bf(f2[j]); v[3] = f2bf(f3[j]);
        *(bf16x4*)(T + q * 128 + ((mr * 8) ^ ((q & 15) << 3))) = v;
    }
    __syncthreads();

    __hip_bfloat16* og = xT + ((size_t)n * HW + q0) * CIN + c0;
#pragma unroll
    for (int it = 0; it < 2; ++it) {
        int ch = it * 256 + tid, rr = ch >> 3, o8 = ch & 7;
        int sw = (rr & 15) << 3;
        bf16x4 lo = *(const bf16x4*)(T + rr * 128 + ((o8 * 16) ^ sw));
        bf16x4 hi = *(const bf16x4*)(T + rr * 128 + ((o8 * 16 + 8) ^ sw));
        bf16x8 v; v[0] = lo[0]; v[1] = lo[1]; v[2] = lo[2]; v[3] = lo[3];
                  v[4] = hi[0]; v[5] = hi[1]; v[6] = hi[2]; v[7] = hi[3];
        *(bf16x8*)(og + (size_t)rr * CIN + o8 * 8) = v;
    }
}

// ---------------------------------------------------------------------------
// Kernel 1: proj via MFMA. Q region scaled by QKSCALE (softmax prefold).
// ---------------------------------------------------------------------------
__global__ __launch_bounds__(256) void proj_kernel(const __hip_bfloat16* __restrict__ xT,
                                                   const __hip_bfloat16* __restrict__ WwB,
                                                   const float* __restrict__ Wb,
                                                   __hip_bfloat16* __restrict__ Qt,
                                                   __hip_bfloat16* __restrict__ Kt,
                                                   __hip_bfloat16* __restrict__ Vg) {
    const int n  = blockIdx.z;
    const int m0 = blockIdx.y * 64;
    const int q0 = blockIdx.x * 64;
    const int tid = threadIdx.x;
    const int lane = tid & 63, wv = tid >> 6;
    const int lr = lane & 15, hi = lane >> 4;

    __shared__ char Aw[64 * 128];
    __shared__ char Bx[64 * 128];
    __shared__ char Ts[64 * 128];

    f32x4 acc[4] = {};
    const __hip_bfloat16* xn = xT + ((size_t)n * HW + q0) * CIN;

    for (int k0 = 0; k0 < CIN; k0 += 64) {
#pragma unroll
        for (int it = 0; it < 2; ++it) {
            int ch = it * 256 + tid, r = ch >> 3, o = ch & 7;
            int sw = (o * 16) ^ ((r & 7) << 4);
            bf16x8 a = *(const bf16x8*)(WwB + (size_t)(m0 + r) * CIN + k0 + o * 8);
            *(bf16x8*)(Aw + r * 128 + sw) = a;
            bf16x8 b = *(const bf16x8*)(xn + (size_t)r * CIN + k0 + o * 8);
            *(bf16x8*)(Bx + r * 128 + sw) = b;
        }
        __syncthreads();

        const int mrow = wv * 16 + lr;
#pragma unroll
        for (int ks = 0; ks < 2; ++ks) {
            bf16x8 af = *(const bf16x8*)(Aw + mrow * 128 +
                                         ((ks * 64 + hi * 16) ^ ((mrow & 7) << 4)));
#pragma unroll
            for (int kn = 0; kn < 4; ++kn) {
                int qrow = kn * 16 + lr;
                bf16x8 bfr = *(const bf16x8*)(Bx + qrow * 128 +
                                              ((ks * 64 + hi * 16) ^ ((qrow & 7) << 4)));
                acc[kn] = MFMA16(af, bfr, acc[kn]);
            }
        }
        __syncthreads();
    }

    const int region = m0 >> 7;     // 0=Q, 1=K, 2=V
    const int c0     = m0 & 127;
    const float oscale = (region == 0) ? QKSCALE : 1.0f;

    float bias[4];
#pragma unroll
    for (int reg = 0; reg < 4; ++reg) bias[reg] = Wb[m0 + wv * 16 + hi * 4 + reg];

#pragma unroll
    for (int kn = 0; kn < 4; ++kn)
#pragma unroll
        for (int reg = 0; reg < 4; ++reg) {
            __hip_bfloat16 v = __float2bfloat16((acc[kn][reg] + bias[reg]) * oscale);
            int row, colb;
            if (region < 2) { row = kn * 16 + lr; colb = (wv * 16 + hi * 4 + reg) * 2; }
            else            { row = wv * 16 + hi * 4 + reg; colb = (kn * 16 + lr) * 2; }
            *(__hip_bfloat16*)(Ts + row * 128 + (colb ^ ((row & 7) << 4))) = v;
        }
    __syncthreads();

    __hip_bfloat16* base;
    size_t rstride;
    if (region == 0)      { base = Qt + (size_t)n * HW * CH + (size_t)q0 * CH + c0; rstride = CH; }
    else if (region == 1) { base = Kt + (size_t)n * HW * CH + (size_t)q0 * CH + c0; rstride = CH; }
    else                  { base = Vg + (size_t)n * CH * HW + (size_t)c0 * HW + q0; rstride = HW; }

#pragma unroll
    for (int it = 0; it < 2; ++it) {
        int ch = it * 256 + tid, rr = ch >> 3, o = ch & 7;
        bf16x8 v = *(const bf16x8*)(Ts + rr * 128 + ((o * 16) ^ ((rr & 7) << 4)));
        *(bf16x8*)(base + (size_t)rr * rstride + o * 8) = v;
    }
}

// ---------------------------------------------------------------------------
// Kernel 2: flash attention, 32x32x16 MFMA. 2 waves x 32q, KVBLK=64.
// K staged in LDS (granule swizzle g ^ (r&7) ^ ((r>>3&1)<<3)); V from global.
// S^T = mfma(K, Q): lane q=lane&31, k rows = (reg&3)+8*(reg>>2)+4*(lane>>5).
// O^T = mfma(V, P^T): rows c, col q. Unnormalized O~ + m,l partials out.
// ---------------------------------------------------------------------------
__global__ __launch_bounds__(128, 3) void attn_kernel(
        const __hip_bfloat16* __restrict__ Qt,   // [NB][HW][CH], pre-scaled
        const __hip_bfloat16* __restrict__ Kt,   // [NB][HW][CH]
        const __hip_bfloat16* __restrict__ Vg,   // [NB][CH][HW]
        __hip_bfloat16* __restrict__ PO,         // [NSPLIT][NB][HW][CH]
        float* __restrict__ Mbuf,                // [NSPLIT][NB][HW] (exp2 domain)
        float* __restrict__ Lbuf) {
    const int n = blockIdx.y, s = blockIdx.z;
    const int q0 = blockIdx.x * 64;
    const int tid = threadIdx.x;             // 0..127
    const int lane = tid & 63, wv = tid >> 6;
    const int l31 = lane & 31, h = lane >> 5;

    __shared__ char Ks[64 * 256];            // [64 k][16 granules of 16B]

    const int t0 = (s == 0) ? 0 : (13 + 12 * (s - 1));
    const int t1 = t0 + ((s == 0) ? 13 : 12);

    const __hip_bfloat16* Kg = Kt + (size_t)n * HW * CH;
    const __hip_bfloat16* Vp = Vg + (size_t)n * CH * HW;

    // Q fragments: lane holds q = q0 + wv*32 + l31, c = cs*16 + h*8 + j
    const __hip_bfloat16* Qg = Qt + ((size_t)n * HW + q0 + wv * 32 + l31) * CH + h * 8;
    bf16x8 qf[8];
#pragma unroll
    for (int cs = 0; cs < 8; ++cs) qf[cs] = *(const bf16x8*)(Qg + cs * 16);

    // K staging: thread stages row = tid>>1, granules (tid&1)*8 + i
    const int krow  = tid >> 1;
    const int kgb   = (tid & 1) * 8;
    const int kswz  = (krow & 7) ^ (((krow >> 3) & 1) << 3);
    const __hip_bfloat16* Ksrc0 = Kg + (size_t)krow * CH + kgb * 8;
    char* Kdst = Ks + krow * 256;

    // fragment-read swizzle (same formula; rows l31 and l31+32 share it)
    const int rsw = (l31 & 7) ^ (((l31 >> 3) & 1) << 3);

    f32x16 O[4] = {};            // O^T: c = ct*32 + crow(reg,h), q = l31
    float m_i = -1e30f, l_i = 0.f;

    for (int t = t0; t < t1; ++t) {
        // ---- stage K tile [64k][128c] (synchronous)
        const __hip_bfloat16* ksrc = Ksrc0 + (size_t)t * 64 * CH;
#pragma unroll
        for (int i = 0; i < 8; ++i) {
            bf16x8 v = *(const bf16x8*)(ksrc + i * 8);
            *(bf16x8*)(Kdst + ((kgb + i) ^ kswz) * 16) = v;
        }
        __syncthreads();

        // ---- S^T = K Q^T (2 k-subtiles of 32)
        f32x16 sa0 = {}, sa1 = {};
#pragma unroll
        for (int cs = 0; cs < 8; ++cs) {
            int goff = ((cs * 2 + h) ^ rsw) * 16;
            bf16x8 k0f = *(const bf16x8*)(Ks + l31 * 256 + goff);
            bf16x8 k1f = *(const bf16x8*)(Ks + (32 + l31) * 256 + goff);
            sa0 = MFMA32(k0f, qf[cs], sa0);
            sa1 = MFMA32(k1f, qf[cs], sa1);
        }

        // ---- online softmax (per-lane q; single cross-half shuffle)
        float pmax = sa0[0];
#pragma unroll
        for (int r = 0; r < 16; ++r) {
            pmax = fmaxf(pmax, sa0[r]);
            pmax = fmaxf(pmax, sa1[r]);
        }
        pmax = fmaxf(pmax, __shfl_xor(pmax, 32));

        if (__any(pmax > m_i)) {
            float nm = fmaxf(m_i, pmax);
            float f  = exp2a(m_i - nm);
            l_i *= f; m_i = nm;
#pragma unroll
            for (int ct = 0; ct < 4; ++ct)
#pragma unroll
                for (int r = 0; r < 16; ++r) O[ct][r] *= f;
        }

        float rs = 0.f;
#pragma unroll
        for (int r = 0; r < 16; ++r) {
            sa0[r] = exp2a(sa0[r] - m_i); rs += sa0[r];
            sa1[r] = exp2a(sa1[r] - m_i); rs += sa1[r];
        }
        rs += __shfl_xor(rs, 32);
        l_i += rs;

        // ---- pack P and build PV B-frags (k-slices of 16) via lane+-32 swap
        union { unsigned u[4]; bf16x8 v; } pf0, pf1, pf2, pf3;
        {
            unsigned w0 = pack2bf(sa0[0],  sa0[1]),  w1 = pack2bf(sa0[2],  sa0[3]);
            unsigned w2 = pack2bf(sa0[4],  sa0[5]),  w3 = pack2bf(sa0[6],  sa0[7]);
            unsigned w4 = pack2bf(sa0[8],  sa0[9]),  w5 = pack2bf(sa0[10], sa0[11]);
            unsigned w6 = pack2bf(sa0[12], sa0[13]), w7 = pack2bf(sa0[14], sa0[15]);
            unsigned x0 = __shfl_xor((int)w0, 32), x1 = __shfl_xor((int)w1, 32);
            unsigned x2 = __shfl_xor((int)w2, 32), x3 = __shfl_xor((int)w3, 32);
            unsigned x4 = __shfl_xor((int)w4, 32), x5 = __shfl_xor((int)w5, 32);
            unsigned x6 = __shfl_xor((int)w6, 32), x7 = __shfl_xor((int)w7, 32);
            pf0.u[0] = h ? x2 : w0; pf0.u[1] = h ? x3 : w1;
            pf0.u[2] = h ? w2 : x0; pf0.u[3] = h ? w3 : x1;
            pf1.u[0] = h ? x6 : w4; pf1.u[1] = h ? x7 : w5;
            pf1.u[2] = h ? w6 : x4; pf1.u[3] = h ? w7 : x5;
        }
        {
            unsigned w0 = pack2bf(sa1[0],  sa1[1]),  w1 = pack2bf(sa1[2],  sa1[3]);
            unsigned w2 = pack2bf(sa1[4],  sa1[5]),  w3 = pack2bf(sa1[6],  sa1[7]);
            unsigned w4 = pack2bf(sa1[8],  sa1[9]),  w5 = pack2bf(sa1[10], sa1[11]);
            unsigned w6 = pack2bf(sa1[12], sa1[13]), w7 = pack2bf(sa1[14], sa1[15]);
            unsigned x0 = __shfl_xor((int)w0, 32), x1 = __shfl_xor((int)w1, 32);
            unsigned x2 = __shfl_xor((int)w2, 32), x3 = __shfl_xor((int)w3, 32);
            unsigned x4 = __shfl_xor((int)w4, 32), x5 = __shfl_xor((int)w5, 32);
            unsigned x6 = __shfl_xor((int)w6, 32), x7 = __shfl_xor((int)w7, 32);
            pf2.u[0] = h ? x2 : w0; pf2.u[1] = h ? x3 : w1;
            pf2.u[2] = h ? w2 : x0; pf2.u[3] = h ? w3 : x1;
            pf3.u[0] = h ? x6 : w4; pf3.u[1] = h ? x7 : w5;
            pf3.u[2] = h ? w6 : x4; pf3.u[3] = h ? w7 : x5;
        }

        // ---- O^T += V P^T ; V A-frags straight from global (L2/L3 resident)
        const __hip_bfloat16* vb0 = Vp + (size_t)l31 * HW + (size_t)t * 64 + h * 8;
#pragma unroll
        for (int ct = 0; ct < 4; ++ct) {
            const __hip_bfloat16* vb = vb0 + (size_t)ct * 32 * HW;
            bf16x8 v0 = *(const bf16x8*)(vb);
            bf16x8 v1 = *(const bf16x8*)(vb + 16);
            bf16x8 v2 = *(const bf16x8*)(vb + 32);
            bf16x8 v3 = *(const bf16x8*)(vb + 48);
            O[ct] = MFMA32(v0, pf0.v, O[ct]);
            O[ct] = MFMA32(v1, pf1.v, O[ct]);
            O[ct] = MFMA32(v2, pf2.v, O[ct]);
            O[ct] = MFMA32(v3, pf3.v, O[ct]);
        }
        __syncthreads();   // Ks consumed; safe to restage next tile
    }

    // ---- epilogue: unnormalized O~ -> smem [64q][128c] bf16, then coalesced
    const int qrow = wv * 32 + l31;
    const int esw  = (qrow & 7) << 4;
#pragma unroll
    for (int ct = 0; ct < 4; ++ct)
#pragma unroll
        for (int i = 0; i < 8; ++i) {
            int c = ct * 32 + 2 * (i & 1) + 8 * (i >> 1) + 4 * h;
            unsigned u = pack2bf(O[ct][2 * i], O[ct][2 * i + 1]);
            *(unsigned*)(Ks + qrow * 256 + ((c * 2) ^ esw)) = u;
        }
    __syncthreads();
    __hip_bfloat16* pg = PO + ((size_t)(s * NB + n) * HW + q0) * CH;
#pragma unroll
    for (int it = 0; it < 8; ++it) {
        int ch = it * 128 + tid, r = ch >> 4, g = ch & 15;
        bf16x8 v = *(const bf16x8*)(Ks + r * 256 + ((g * 16) ^ ((r & 7) << 4)));
        *(bf16x8*)(pg + (size_t)r * CH + g * 8) = v;
    }
    if (h == 0) {
        size_t base = (size_t)(s * NB + n) * HW + q0 + wv * 32 + l31;
        Mbuf[base] = m_i; Lbuf[base] = l_i;
    }
}

// ---------------------------------------------------------------------------
// Kernel 2b: merge KV-split partials (exp2 domain) -> att bf16 [n][q][c].
// ---------------------------------------------------------------------------
__global__ __launch_bounds__(256) void merge_kernel(
        const __hip_bfloat16* __restrict__ PO,
        const float* __restrict__ Mbuf,
        const float* __restrict__ Lbuf,
        __hip_bfloat16* __restrict__ att) {
    const int idx = blockIdx.x * 256 + threadIdx.x;
    const int nq = idx >> 4;
    const int c0 = (idx & 15) * 8;
    const size_t NHW = (size_t)NB * HW;

    float m[NSPLIT], l[NSPLIT];
#pragma unroll
    for (int s = 0; s < NSPLIT; ++s) { m[s] = Mbuf[s * NHW + nq]; l[s] = Lbuf[s * NHW + nq]; }
    float M = m[0];
#pragma unroll
    for (int s = 1; s < NSPLIT; ++s) M = fmaxf(M, m[s]);
    float w[NSPLIT], denom = 0.f;
#pragma unroll
    for (int s = 0; s < NSPLIT; ++s) { w[s] = exp2f(m[s] - M); denom += w[s] * l[s]; }
    float rinv = 1.f / denom;

    float acc[8] = {};
#pragma unroll
    for (int s = 0; s < NSPLIT; ++s) {
        union { bf16x8 v; unsigned short u[8]; } p;
        p.v = *(const bf16x8*)(PO + (size_t)s * NHW * CH + (size_t)nq * CH + c0);
#pragma unroll
        for (int j = 0; j < 8; ++j) acc[j] += w[s] * bfraw2f(p.u[j]);
    }
    union { bf16x8 v; unsigned short u[8]; } ov;
#pragma unroll
    for (int j = 0; j < 8; ++j) ov.u[j] = (unsigned short)f2bf(acc[j] * rinv);
    *(bf16x8*)(att + (size_t)nq * CH + c0) = ov.v;
}

// ---------------------------------------------------------------------------
// Kernel 3: z = ZwB @ att[n] via MFMA (K=128), BN + residual. Unchanged.
// ---------------------------------------------------------------------------
__global__ __launch_bounds__(256) void zbn_kernel(const __hip_bfloat16* __restrict__ att,
                                                  const __hip_bfloat16* __restrict__ ZwB,
                                                  const float* __restrict__ gamma,
                                                  const float* __restrict__ beta,
                                                  const float* __restrict__ mean,
                                                  const float* __restrict__ var,
                                                  const float* __restrict__ x,
                                                  float* __restrict__ out) {
    const int n  = blockIdx.z;
    const int m0 = blockIdx.y * 64;
    const int q0 = blockIdx.x * 64;
    const int tid = threadIdx.x;
    const int lane = tid & 63, wv = tid >> 6;
    const int lr = lane & 15, hi = lane >> 4;

    __shared__ char smem[32768];
    char* Az = smem;
    char* Ba = smem + 16384;

#pragma unroll
    for (int it = 0; it < 4; ++it) {
        int ch = it * 256 + tid, r = ch >> 4, o = ch & 15;
        int sw = (o * 16) ^ ((r & 7) << 4);
        bf16x8 a = *(const bf16x8*)(ZwB + (size_t)(m0 + r) * CH + o * 8);
        *(bf16x8*)(Az + r * 256 + sw) = a;
        bf16x8 b = *(const bf16x8*)(att + ((size_t)n * HW + q0 + r) * CH + o * 8);
        *(bf16x8*)(Ba + r * 256 + sw) = b;
    }
    __syncthreads();

    f32x4 acc[4] = {};
    const int mrow = wv * 16 + lr;
#pragma unroll
    for (int ks = 0; ks < 4; ++ks) {
        bf16x8 af = *(const bf16x8*)(Az + mrow * 256 +
                                     ((ks * 64 + hi * 16) ^ ((mrow & 7) << 4)));
#pragma unroll
        for (int kn = 0; kn < 4; ++kn) {
            int qrow = kn * 16 + lr;
            bf16x8 bfr = *(const bf16x8*)(Ba + qrow * 256 +
                                          ((ks * 64 + hi * 16) ^ ((qrow & 7) << 4)));
            acc[kn] = MFMA16(af, bfr, acc[kn]);
        }
    }
    __syncthreads();

    float inv[4], add[4];
#pragma unroll
    for (int reg = 0; reg < 4; ++reg) {
        int m = m0 + wv * 16 + hi * 4 + reg;
        inv[reg] = gamma[m] * rsqrtf(var[m] + BNEPS);
        add[reg] = beta[m] - mean[m] * inv[reg];
    }

#pragma unroll
    for (int kn = 0; kn < 4; ++kn)
#pragma unroll
        for (int reg = 0; reg < 4; ++reg) {
            int row = wv * 16 + hi * 4 + reg;
            int colb = (kn * 16 + lr) * 4;
            *(float*)(smem + row * 256 + (colb ^ ((row & 7) << 4))) =
                acc[kn][reg] * inv[reg] + add[reg];
        }
    __syncthreads();

#pragma unroll
    for (int it = 0; it < 4; ++it) {
        int ch = it * 256 + tid, rr = ch >> 4, o = ch & 15;
        f32x4 v = *(const f32x4*)(smem + rr * 256 + ((o * 16) ^ ((rr & 7) << 4)));
        size_t idx = (size_t)n * CIN * HW + (size_t)(m0 + rr) * HW + q0 + o * 4;
        float4 xv = *(const float4*)(x + idx);
        float4 ov; ov.x = v[0] + xv.x; ov.y = v[1] + xv.y;
                   ov.z = v[2] + xv.z; ov.w = v[3] + xv.w;
        *(float4*)(out + idx) = ov;
    }
}

// ---------------------------------------------------------------------------
extern "C" void kernel_launch(void* const* d_in, const int* in_sizes, int n_in,
                              void* d_out, int out_size, void* d_ws, size_t ws_size,
                              hipStream_t stream) {
    const float* x     = (const float*)d_in[0];
    const float* Ww    = (const float*)d_in[1];
    const float* Wb    = (const float*)d_in[2];
    const float* Zw    = (const float*)d_in[3];
    const float* gamma = (const float*)d_in[4];
    const float* beta  = (const float*)d_in[5];
    const float* mean  = (const float*)d_in[6];
    const float* var   = (const float*)d_in[7];
    float* out = (float*)d_out;

    // d_out scratch chain (51.38 MB), all dead before zbn writes out:
    //   [0, 25.69M)    xT        (xpose -> proj)
    //   [25.69, 45.0M) Qt/Kt/Vg  (proj -> attn)
    //   [0, 25.69M)    PO x4     (attn -> merge; overlays dead xT)
    const size_t xT_bytes  = (size_t)NB * HW * CIN * 2;
    const size_t qkv_bytes = (size_t)NB * HW * CH * 2;
    char* ob = (char*)d_out;
    __hip_bfloat16* xT  = (__hip_bfloat16*)ob;
    __hip_bfloat16* Qt  = (__hip_bfloat16*)(ob + xT_bytes);
    __hip_bfloat16* Kt  = (__hip_bfloat16*)(ob + xT_bytes + qkv_bytes);
    __hip_bfloat16* Vgb = (__hip_bfloat16*)(ob + xT_bytes + 2 * qkv_bytes);
    __hip_bfloat16* PO  = (__hip_bfloat16*)ob;

    char* w = (char*)d_ws;
    __hip_bfloat16* attb = (__hip_bfloat16*)w;                       w += qkv_bytes;
    __hip_bfloat16* WwB  = (__hip_bfloat16*)w;                       w += (size_t)TCH * CIN * 2;
    __hip_bfloat16* ZwB  = (__hip_bfloat16*)w;                       w += (size_t)CIN * CH * 2;
    float* Mbuf = (float*)w;                                         w += (size_t)NSPLIT * NB * HW * 4;
    float* Lbuf = (float*)w;

    cvt_wts<<<dim3(256), 256, 0, stream>>>(Ww, Zw, WwB, ZwB);
    xpose_kernel<<<dim3(HW / 64, CIN / 64, NB), 256, 0, stream>>>(x, xT);
    proj_kernel<<<dim3(HW / 64, TCH / 64, NB), 256, 0, stream>>>(xT, WwB, Wb, Qt, Kt, Vgb);
    attn_kernel<<<dim3(HW / 64, NB, NSPLIT), 128, 0, stream>>>(Qt, Kt, Vgb, PO, Mbuf, Lbuf);
    merge_kernel<<<dim3(NB * HW * 16 / 256), 256, 0, stream>>>(PO, Mbuf, Lbuf, attb);
    zbn_kernel<<<dim3(HW / 64, CIN / 64, NB), 256, 0, stream>>>(attb, ZwB, gamma, beta,
                                                                mean, var, x, out);
}

// Round 8
// 150.809 us; speedup vs baseline: 1.4507x; 1.4507x over previous
//
#include <hip/hip_runtime.h>
#include <hip/hip_bf16.h>
#include <math.h>

// Problem constants
#define NB    8          // batch
#define CIN   512        // in channels
#define HW    3136       // 56*56
#define CH    128        // attention channels
#define TCH   384        // 3*CH
#define SCALE 0.08838834764831845f   // 128^-0.5
#define QKSCALE 0.12751744f          // SCALE * log2(e), folded into Q at proj time
#define BNEPS 1e-5f
#define NSPLIT 4         // KV splits (49 tiles of 64 -> 13/12/12/12)
#define QB    128        // q rows per attn block (4 waves x 32)

typedef __attribute__((ext_vector_type(8)))  short bf16x8;
typedef __attribute__((ext_vector_type(4)))  short bf16x4;
typedef __attribute__((ext_vector_type(4)))  float f32x4;
typedef __attribute__((ext_vector_type(16))) float f32x16;

#define MFMA16(a, b, c) __builtin_amdgcn_mfma_f32_16x16x32_bf16((a), (b), (c), 0, 0, 0)
#define MFMA32(a, b, c) __builtin_amdgcn_mfma_f32_32x32x16_bf16((a), (b), (c), 0, 0, 0)

__device__ inline short f2bf(float f) {
    __hip_bfloat16 h = __float2bfloat16(f);
    return *reinterpret_cast<short*>(&h);
}
__device__ inline unsigned pack2bf(float a, float b) {
    return (unsigned)(unsigned short)f2bf(a) | ((unsigned)(unsigned short)f2bf(b) << 16);
}
__device__ inline float bfraw2f(unsigned short u) {
    return __uint_as_float(((unsigned)u) << 16);
}
__device__ inline float exp2a(float x) {           // raw v_exp_f32 (2^x)
    float r; asm("v_exp_f32 %0, %1" : "=v"(r) : "v"(x)); return r;
}

// ---------------------------------------------------------------------------
// Kernel 0a: convert Ww and Zw f32 -> bf16.
// ---------------------------------------------------------------------------
__global__ __launch_bounds__(256) void cvt_wts(const float* __restrict__ Ww,
                                               const float* __restrict__ Zw,
                                               __hip_bfloat16* __restrict__ WwB,
                                               __hip_bfloat16* __restrict__ ZwB) {
    const int nW = TCH * CIN / 4;
    const int nZ = CIN * CH / 4;
    int i = blockIdx.x * 256 + threadIdx.x;
    if (i < nW) {
        float4 v = ((const float4*)Ww)[i];
        bf16x4 o; o[0] = f2bf(v.x); o[1] = f2bf(v.y); o[2] = f2bf(v.z); o[3] = f2bf(v.w);
        ((bf16x4*)WwB)[i] = o;
    } else if (i < nW + nZ) {
        int j = i - nW;
        float4 v = ((const float4*)Zw)[j];
        bf16x4 o; o[0] = f2bf(v.x); o[1] = f2bf(v.y); o[2] = f2bf(v.z); o[3] = f2bf(v.w);
        ((bf16x4*)ZwB)[j] = o;
    }
}

// ---------------------------------------------------------------------------
// Kernel 0b: xT[n][q][c] bf16 = transpose+cvt of x[n][c][q] f32. (unchanged)
// ---------------------------------------------------------------------------
__global__ __launch_bounds__(256) void xpose_kernel(const float* __restrict__ x,
                                                    __hip_bfloat16* __restrict__ xT) {
    const int n = blockIdx.z, c0 = blockIdx.y * 64, q0 = blockIdx.x * 64;
    const int tid = threadIdx.x;
    const int mr = tid >> 4, mq = tid & 15;

    __shared__ char T[64 * 128];

    const float* xp = x + ((size_t)(n * CIN + c0 + mr * 4)) * HW + q0 + mq * 4;
    float4 r0 = *(const float4*)(xp);
    float4 r1 = *(const float4*)(xp + HW);
    float4 r2 = *(const float4*)(xp + 2 * HW);
    float4 r3 = *(const float4*)(xp + 3 * HW);
    const float* f0 = (const float*)&r0; const float* f1 = (const float*)&r1;
    const float* f2 = (const float*)&r2; const float* f3 = (const float*)&r3;
#pragma unroll
    for (int j = 0; j < 4; ++j) {
        int q = mq * 4 + j;
        bf16x4 v; v[0] = f2bf(f0[j]); v[1] = f2bf(f1[j]);
                  v[2] = f2bf(f2[j]); v[3] = f2bf(f3[j]);
        *(bf16x4*)(T + q * 128 + ((mr * 8) ^ ((q & 15) << 3))) = v;
    }
    __syncthreads();

    __hip_bfloat16* og = xT + ((size_t)n * HW + q0) * CIN + c0;
#pragma unroll
    for (int it = 0; it < 2; ++it) {
        int ch = it * 256 + tid, rr = ch >> 3, o8 = ch & 7;
        int sw = (rr & 15) << 3;
        bf16x4 lo = *(const bf16x4*)(T + rr * 128 + ((o8 * 16) ^ sw));
        bf16x4 hi = *(const bf16x4*)(T + rr * 128 + ((o8 * 16 + 8) ^ sw));
        bf16x8 v; v[0] = lo[0]; v[1] = lo[1]; v[2] = lo[2]; v[3] = lo[3];
                  v[4] = hi[0]; v[5] = hi[1]; v[6] = hi[2]; v[7] = hi[3];
        *(bf16x8*)(og + (size_t)rr * CIN + o8 * 8) = v;
    }
}

// ---------------------------------------------------------------------------
// Kernel 1: proj via MFMA. Q region scaled by QKSCALE. (unchanged)
// ---------------------------------------------------------------------------
__global__ __launch_bounds__(256) void proj_kernel(const __hip_bfloat16* __restrict__ xT,
                                                   const __hip_bfloat16* __restrict__ WwB,
                                                   const float* __restrict__ Wb,
                                                   __hip_bfloat16* __restrict__ Qt,
                                                   __hip_bfloat16* __restrict__ Kt,
                                                   __hip_bfloat16* __restrict__ Vg) {
    const int n  = blockIdx.z;
    const int m0 = blockIdx.y * 64;
    const int q0 = blockIdx.x * 64;
    const int tid = threadIdx.x;
    const int lane = tid & 63, wv = tid >> 6;
    const int lr = lane & 15, hi = lane >> 4;

    __shared__ char Aw[64 * 128];
    __shared__ char Bx[64 * 128];
    __shared__ char Ts[64 * 128];

    f32x4 acc[4] = {};
    const __hip_bfloat16* xn = xT + ((size_t)n * HW + q0) * CIN;

    for (int k0 = 0; k0 < CIN; k0 += 64) {
#pragma unroll
        for (int it = 0; it < 2; ++it) {
            int ch = it * 256 + tid, r = ch >> 3, o = ch & 7;
            int sw = (o * 16) ^ ((r & 7) << 4);
            bf16x8 a = *(const bf16x8*)(WwB + (size_t)(m0 + r) * CIN + k0 + o * 8);
            *(bf16x8*)(Aw + r * 128 + sw) = a;
            bf16x8 b = *(const bf16x8*)(xn + (size_t)r * CIN + k0 + o * 8);
            *(bf16x8*)(Bx + r * 128 + sw) = b;
        }
        __syncthreads();

        const int mrow = wv * 16 + lr;
#pragma unroll
        for (int ks = 0; ks < 2; ++ks) {
            bf16x8 af = *(const bf16x8*)(Aw + mrow * 128 +
                                         ((ks * 64 + hi * 16) ^ ((mrow & 7) << 4)));
#pragma unroll
            for (int kn = 0; kn < 4; ++kn) {
                int qrow = kn * 16 + lr;
                bf16x8 bfr = *(const bf16x8*)(Bx + qrow * 128 +
                                              ((ks * 64 + hi * 16) ^ ((qrow & 7) << 4)));
                acc[kn] = MFMA16(af, bfr, acc[kn]);
            }
        }
        __syncthreads();
    }

    const int region = m0 >> 7;     // 0=Q, 1=K, 2=V
    const int c0     = m0 & 127;
    const float oscale = (region == 0) ? QKSCALE : 1.0f;

    float bias[4];
#pragma unroll
    for (int reg = 0; reg < 4; ++reg) bias[reg] = Wb[m0 + wv * 16 + hi * 4 + reg];

#pragma unroll
    for (int kn = 0; kn < 4; ++kn)
#pragma unroll
        for (int reg = 0; reg < 4; ++reg) {
            __hip_bfloat16 v = __float2bfloat16((acc[kn][reg] + bias[reg]) * oscale);
            int row, colb;
            if (region < 2) { row = kn * 16 + lr; colb = (wv * 16 + hi * 4 + reg) * 2; }
            else            { row = wv * 16 + hi * 4 + reg; colb = (kn * 16 + lr) * 2; }
            *(__hip_bfloat16*)(Ts + row * 128 + (colb ^ ((row & 7) << 4))) = v;
        }
    __syncthreads();

    __hip_bfloat16* base;
    size_t rstride;
    if (region == 0)      { base = Qt + (size_t)n * HW * CH + (size_t)q0 * CH + c0; rstride = CH; }
    else if (region == 1) { base = Kt + (size_t)n * HW * CH + (size_t)q0 * CH + c0; rstride = CH; }
    else                  { base = Vg + (size_t)n * CH * HW + (size_t)c0 * HW + q0; rstride = HW; }

#pragma unroll
    for (int it = 0; it < 2; ++it) {
        int ch = it * 256 + tid, rr = ch >> 3, o = ch & 7;
        bf16x8 v = *(const bf16x8*)(Ts + rr * 128 + ((o * 16) ^ ((rr & 7) << 4)));
        *(bf16x8*)(base + (size_t)rr * rstride + o * 8) = v;
    }
}

// ---------------------------------------------------------------------------
// Kernel 2: flash attention, 32x32x16 MFMA, 4 waves x 32q (QB=128), KVBLK=64.
// K AND V staged in LDS with register prefetch (R6 pattern). V gathers from
// global removed (R7 regression: 32-line address divergence per instruction).
// ---------------------------------------------------------------------------
__global__ __launch_bounds__(256, 2) void attn_kernel(
        const __hip_bfloat16* __restrict__ Qt,   // [NB][HW][CH], pre-scaled
        const __hip_bfloat16* __restrict__ Kt,   // [NB][HW][CH]
        const __hip_bfloat16* __restrict__ Vg,   // [NB][CH][HW]
        __hip_bfloat16* __restrict__ PO,         // [NSPLIT][NB][HW][CH]
        float* __restrict__ Mbuf,                // [NSPLIT][NB][HW] (exp2 domain)
        float* __restrict__ Lbuf) {
    const int n = blockIdx.y, s = blockIdx.z;
    const int q0 = blockIdx.x * QB;
    const int tid = threadIdx.x;             // 0..255
    const int lane = tid & 63, wv = tid >> 6;
    const int l31 = lane & 31, h = lane >> 5;

    __shared__ char smem[32768];
    char* Ks = smem;            // [64 k][16 granules of 16B], 4-bit granule swz
    char* Vt = smem + 16384;    // [128 c][8 granules of 16B], 3-bit granule swz

    const int t0 = (s == 0) ? 0 : (13 + 12 * (s - 1));
    const int t1 = t0 + ((s == 0) ? 13 : 12);

    const __hip_bfloat16* Kg = Kt + (size_t)n * HW * CH;
    const __hip_bfloat16* Vp = Vg + (size_t)n * CH * HW;

    // Q fragments: lane q = q0 + wv*32 + l31 (clamped in tail block)
    const int qg = q0 + wv * 32 + l31;
    const int qc = (qg < HW) ? qg : (HW - 1);
    const __hip_bfloat16* Qg = Qt + ((size_t)n * HW + qc) * CH + h * 8;
    bf16x8 qf[8];
#pragma unroll
    for (int cs = 0; cs < 8; ++cs) qf[cs] = *(const bf16x8*)(Qg + cs * 16);

    // staging geometry: K 64x256B (4 thr/row, 4 granules each),
    //                   V 128x128B (2 thr/row, 4 granules each)
    const int kr = tid >> 2, kgb = (tid & 3) * 4;
    const int ksz = (kr & 7) ^ (((kr >> 3) & 1) << 3);
    const int vr = tid >> 1, vgb = (tid & 1) * 4;
    const int vsz = vr & 7;
    const __hip_bfloat16* Ksrc = Kg + (size_t)kr * CH;
    const __hip_bfloat16* Vsrc = Vp + (size_t)vr * HW;
    char* Kd = Ks + kr * 256;
    char* Vd = Vt + vr * 128;

    bf16x8 kreg[4], vreg[4];
    {
        const int kk = t0 * 64;
#pragma unroll
        for (int i = 0; i < 4; ++i)
            kreg[i] = *(const bf16x8*)(Ksrc + (size_t)kk * CH + (kgb + i) * 8);
#pragma unroll
        for (int i = 0; i < 4; ++i)
            vreg[i] = *(const bf16x8*)(Vsrc + kk + (vgb + i) * 8);
    }
#pragma unroll
    for (int i = 0; i < 4; ++i) *(bf16x8*)(Kd + ((kgb + i) ^ ksz) * 16) = kreg[i];
#pragma unroll
    for (int i = 0; i < 4; ++i) *(bf16x8*)(Vd + ((vgb + i) ^ vsz) * 16) = vreg[i];
    __syncthreads();

    // fragment-read swizzle for K rows (rows r and r+32 share the value)
    const int rsw = (l31 & 7) ^ (((l31 >> 3) & 1) << 3);
    const int vrsw = l31 & 7;   // V rows ct*32+l31 share (row&7) = l31&7

    f32x16 O[4] = {};            // O^T: c = ct*32 + crow(reg,h), q = l31
    float m_i = -1e30f, l_i = 0.f;

    for (int t = t0; t < t1; ++t) {
        // prefetch next tile into registers (hides under MFMA+softmax)
        if (t + 1 < t1) {
            const int kk = (t + 1) * 64;
#pragma unroll
            for (int i = 0; i < 4; ++i)
                kreg[i] = *(const bf16x8*)(Ksrc + (size_t)kk * CH + (kgb + i) * 8);
#pragma unroll
            for (int i = 0; i < 4; ++i)
                vreg[i] = *(const bf16x8*)(Vsrc + kk + (vgb + i) * 8);
        }

        // ---- S^T = K Q^T (2 k-subtiles of 32)
        f32x16 sa0 = {}, sa1 = {};
#pragma unroll
        for (int cs = 0; cs < 8; ++cs) {
            int goff = ((cs * 2 + h) ^ rsw) * 16;
            bf16x8 k0f = *(const bf16x8*)(Ks + l31 * 256 + goff);
            bf16x8 k1f = *(const bf16x8*)(Ks + (32 + l31) * 256 + goff);
            sa0 = MFMA32(k0f, qf[cs], sa0);
            sa1 = MFMA32(k1f, qf[cs], sa1);
        }

        // ---- online softmax (per-lane q; single cross-half shuffle)
        float pmax = sa0[0];
#pragma unroll
        for (int r = 0; r < 16; ++r) {
            pmax = fmaxf(pmax, sa0[r]);
            pmax = fmaxf(pmax, sa1[r]);
        }
        pmax = fmaxf(pmax, __shfl_xor(pmax, 32));

        if (__any(pmax > m_i)) {
            float nm = fmaxf(m_i, pmax);
            float f  = exp2a(m_i - nm);
            l_i *= f; m_i = nm;
#pragma unroll
            for (int ct = 0; ct < 4; ++ct)
#pragma unroll
                for (int r = 0; r < 16; ++r) O[ct][r] *= f;
        }

        float rs = 0.f;
#pragma unroll
        for (int r = 0; r < 16; ++r) {
            sa0[r] = exp2a(sa0[r] - m_i); rs += sa0[r];
            sa1[r] = exp2a(sa1[r] - m_i); rs += sa1[r];
        }
        rs += __shfl_xor(rs, 32);
        l_i += rs;

        // ---- pack P, build PV B-frags via lane+-32 swap
        union { unsigned u[4]; bf16x8 v; } pf0, pf1, pf2, pf3;
        {
            unsigned w0 = pack2bf(sa0[0],  sa0[1]),  w1 = pack2bf(sa0[2],  sa0[3]);
            unsigned w2 = pack2bf(sa0[4],  sa0[5]),  w3 = pack2bf(sa0[6],  sa0[7]);
            unsigned w4 = pack2bf(sa0[8],  sa0[9]),  w5 = pack2bf(sa0[10], sa0[11]);
            unsigned w6 = pack2bf(sa0[12], sa0[13]), w7 = pack2bf(sa0[14], sa0[15]);
            unsigned x0 = __shfl_xor((int)w0, 32), x1 = __shfl_xor((int)w1, 32);
            unsigned x2 = __shfl_xor((int)w2, 32), x3 = __shfl_xor((int)w3, 32);
            unsigned x4 = __shfl_xor((int)w4, 32), x5 = __shfl_xor((int)w5, 32);
            unsigned x6 = __shfl_xor((int)w6, 32), x7 = __shfl_xor((int)w7, 32);
            pf0.u[0] = h ? x2 : w0; pf0.u[1] = h ? x3 : w1;
            pf0.u[2] = h ? w2 : x0; pf0.u[3] = h ? w3 : x1;
            pf1.u[0] = h ? x6 : w4; pf1.u[1] = h ? x7 : w5;
            pf1.u[2] = h ? w6 : x4; pf1.u[3] = h ? w7 : x5;
        }
        {
            unsigned w0 = pack2bf(sa1[0],  sa1[1]),  w1 = pack2bf(sa1[2],  sa1[3]);
            unsigned w2 = pack2bf(sa1[4],  sa1[5]),  w3 = pack2bf(sa1[6],  sa1[7]);
            unsigned w4 = pack2bf(sa1[8],  sa1[9]),  w5 = pack2bf(sa1[10], sa1[11]);
            unsigned w6 = pack2bf(sa1[12], sa1[13]), w7 = pack2bf(sa1[14], sa1[15]);
            unsigned x0 = __shfl_xor((int)w0, 32), x1 = __shfl_xor((int)w1, 32);
            unsigned x2 = __shfl_xor((int)w2, 32), x3 = __shfl_xor((int)w3, 32);
            unsigned x4 = __shfl_xor((int)w4, 32), x5 = __shfl_xor((int)w5, 32);
            unsigned x6 = __shfl_xor((int)w6, 32), x7 = __shfl_xor((int)w7, 32);
            pf2.u[0] = h ? x2 : w0; pf2.u[1] = h ? x3 : w1;
            pf2.u[2] = h ? w2 : x0; pf2.u[3] = h ? w3 : x1;
            pf3.u[0] = h ? x6 : w4; pf3.u[1] = h ? x7 : w5;
            pf3.u[2] = h ? w6 : x4; pf3.u[3] = h ? w7 : x5;
        }

        // ---- O^T += V P^T ; V A-frags from LDS (logical granule 2*ks+h)
#pragma unroll
        for (int ct = 0; ct < 4; ++ct) {
            const char* vrow = Vt + (ct * 32 + l31) * 128;
            bf16x8 v0 = *(const bf16x8*)(vrow + ((0 + h) ^ vrsw) * 16);
            bf16x8 v1 = *(const bf16x8*)(vrow + ((2 + h) ^ vrsw) * 16);
            bf16x8 v2 = *(const bf16x8*)(vrow + ((4 + h) ^ vrsw) * 16);
            bf16x8 v3 = *(const bf16x8*)(vrow + ((6 + h) ^ vrsw) * 16);
            O[ct] = MFMA32(v0, pf0.v, O[ct]);
            O[ct] = MFMA32(v1, pf1.v, O[ct]);
            O[ct] = MFMA32(v2, pf2.v, O[ct]);
            O[ct] = MFMA32(v3, pf3.v, O[ct]);
        }

        __syncthreads();              // all waves done reading Ks/Vt
        if (t + 1 < t1) {
#pragma unroll
            for (int i = 0; i < 4; ++i) *(bf16x8*)(Kd + ((kgb + i) ^ ksz) * 16) = kreg[i];
#pragma unroll
            for (int i = 0; i < 4; ++i) *(bf16x8*)(Vd + ((vgb + i) ^ vsz) * 16) = vreg[i];
        }
        __syncthreads();
    }

    // ---- epilogue: unnormalized O~ -> smem [128 q][256B] bf16, coalesced out
    const int qrow = wv * 32 + l31;
    const int esw  = (qrow & 7) << 4;
#pragma unroll
    for (int ct = 0; ct < 4; ++ct)
#pragma unroll
        for (int i = 0; i < 8; ++i) {
            int c = ct * 32 + 2 * (i & 1) + 8 * (i >> 1) + 4 * h;
            unsigned u = pack2bf(O[ct][2 * i], O[ct][2 * i + 1]);
            *(unsigned*)(smem + qrow * 256 + ((c * 2) ^ esw)) = u;
        }
    __syncthreads();
    __hip_bfloat16* pg = PO + ((size_t)(s * NB + n) * HW + q0) * CH;
#pragma unroll
    for (int it = 0; it < 8; ++it) {
        int ch = it * 256 + tid, r = ch >> 4, g = ch & 15;
        if (q0 + r < HW) {
            bf16x8 v = *(const bf16x8*)(smem + r * 256 + ((g * 16) ^ ((r & 7) << 4)));
            *(bf16x8*)(pg + (size_t)r * CH + g * 8) = v;
        }
    }
    if (h == 0 && qg < HW) {
        size_t base = (size_t)(s * NB + n) * HW + qg;
        Mbuf[base] = m_i; Lbuf[base] = l_i;
    }
}

// ---------------------------------------------------------------------------
// Kernel 2b: merge KV-split partials (exp2 domain) -> att bf16 [n][q][c].
// ---------------------------------------------------------------------------
__global__ __launch_bounds__(256) void merge_kernel(
        const __hip_bfloat16* __restrict__ PO,
        const float* __restrict__ Mbuf,
        const float* __restrict__ Lbuf,
        __hip_bfloat16* __restrict__ att) {
    const int idx = blockIdx.x * 256 + threadIdx.x;
    const int nq = idx >> 4;
    const int c0 = (idx & 15) * 8;
    const size_t NHW = (size_t)NB * HW;

    float m[NSPLIT], l[NSPLIT];
#pragma unroll
    for (int s = 0; s < NSPLIT; ++s) { m[s] = Mbuf[s * NHW + nq]; l[s] = Lbuf[s * NHW + nq]; }
    float M = m[0];
#pragma unroll
    for (int s = 1; s < NSPLIT; ++s) M = fmaxf(M, m[s]);
    float w[NSPLIT], denom = 0.f;
#pragma unroll
    for (int s = 0; s < NSPLIT; ++s) { w[s] = exp2f(m[s] - M); denom += w[s] * l[s]; }
    float rinv = 1.f / denom;

    float acc[8] = {};
#pragma unroll
    for (int s = 0; s < NSPLIT; ++s) {
        union { bf16x8 v; unsigned short u[8]; } p;
        p.v = *(const bf16x8*)(PO + (size_t)s * NHW * CH + (size_t)nq * CH + c0);
#pragma unroll
        for (int j = 0; j < 8; ++j) acc[j] += w[s] * bfraw2f(p.u[j]);
    }
    union { bf16x8 v; unsigned short u[8]; } ov;
#pragma unroll
    for (int j = 0; j < 8; ++j) ov.u[j] = (unsigned short)f2bf(acc[j] * rinv);
    *(bf16x8*)(att + (size_t)nq * CH + c0) = ov.v;
}

// ---------------------------------------------------------------------------
// Kernel 3: z = ZwB @ att[n] via MFMA (K=128), BN + residual. Unchanged.
// ---------------------------------------------------------------------------
__global__ __launch_bounds__(256) void zbn_kernel(const __hip_bfloat16* __restrict__ att,
                                                  const __hip_bfloat16* __restrict__ ZwB,
                                                  const float* __restrict__ gamma,
                                                  const float* __restrict__ beta,
                                                  const float* __restrict__ mean,
                                                  const float* __restrict__ var,
                                                  const float* __restrict__ x,
                                                  float* __restrict__ out) {
    const int n  = blockIdx.z;
    const int m0 = blockIdx.y * 64;
    const int q0 = blockIdx.x * 64;
    const int tid = threadIdx.x;
    const int lane = tid & 63, wv = tid >> 6;
    const int lr = lane & 15, hi = lane >> 4;

    __shared__ char smem[32768];
    char* Az = smem;
    char* Ba = smem + 16384;

#pragma unroll
    for (int it = 0; it < 4; ++it) {
        int ch = it * 256 + tid, r = ch >> 4, o = ch & 15;
        int sw = (o * 16) ^ ((r & 7) << 4);
        bf16x8 a = *(const bf16x8*)(ZwB + (size_t)(m0 + r) * CH + o * 8);
        *(bf16x8*)(Az + r * 256 + sw) = a;
        bf16x8 b = *(const bf16x8*)(att + ((size_t)n * HW + q0 + r) * CH + o * 8);
        *(bf16x8*)(Ba + r * 256 + sw) = b;
    }
    __syncthreads();

    f32x4 acc[4] = {};
    const int mrow = wv * 16 + lr;
#pragma unroll
    for (int ks = 0; ks < 4; ++ks) {
        bf16x8 af = *(const bf16x8*)(Az + mrow * 256 +
                                     ((ks * 64 + hi * 16) ^ ((mrow & 7) << 4)));
#pragma unroll
        for (int kn = 0; kn < 4; ++kn) {
            int qrow = kn * 16 + lr;
            bf16x8 bfr = *(const bf16x8*)(Ba + qrow * 256 +
                                          ((ks * 64 + hi * 16) ^ ((qrow & 7) << 4)));
            acc[kn] = MFMA16(af, bfr, acc[kn]);
        }
    }
    __syncthreads();

    float inv[4], add[4];
#pragma unroll
    for (int reg = 0; reg < 4; ++reg) {
        int m = m0 + wv * 16 + hi * 4 + reg;
        inv[reg] = gamma[m] * rsqrtf(var[m] + BNEPS);
        add[reg] = beta[m] - mean[m] * inv[reg];
    }

#pragma unroll
    for (int kn = 0; kn < 4; ++kn)
#pragma unroll
        for (int reg = 0; reg < 4; ++reg) {
            int row = wv * 16 + hi * 4 + reg;
            int colb = (kn * 16 + lr) * 4;
            *(float*)(smem + row * 256 + (colb ^ ((row & 7) << 4))) =
                acc[kn][reg] * inv[reg] + add[reg];
        }
    __syncthreads();

#pragma unroll
    for (int it = 0; it < 4; ++it) {
        int ch = it * 256 + tid, rr = ch >> 4, o = ch & 15;
        f32x4 v = *(const f32x4*)(smem + rr * 256 + ((o * 16) ^ ((rr & 7) << 4)));
        size_t idx = (size_t)n * CIN * HW + (size_t)(m0 + rr) * HW + q0 + o * 4;
        float4 xv = *(const float4*)(x + idx);
        float4 ov; ov.x = v[0] + xv.x; ov.y = v[1] + xv.y;
                   ov.z = v[2] + xv.z; ov.w = v[3] + xv.w;
        *(float4*)(out + idx) = ov;
    }
}

// ---------------------------------------------------------------------------
extern "C" void kernel_launch(void* const* d_in, const int* in_sizes, int n_in,
                              void* d_out, int out_size, void* d_ws, size_t ws_size,
                              hipStream_t stream) {
    const float* x     = (const float*)d_in[0];
    const float* Ww    = (const float*)d_in[1];
    const float* Wb    = (const float*)d_in[2];
    const float* Zw    = (const float*)d_in[3];
    const float* gamma = (const float*)d_in[4];
    const float* beta  = (const float*)d_in[5];
    const float* mean  = (const float*)d_in[6];
    const float* var   = (const float*)d_in[7];
    float* out = (float*)d_out;

    // d_out scratch chain (51.38 MB), all dead before zbn writes out:
    //   [0, 25.69M)    xT        (xpose -> proj)
    //   [25.69, 45.0M) Qt/Kt/Vg  (proj -> attn)
    //   [0, 25.69M)    PO x4     (attn -> merge; overlays dead xT)
    const size_t xT_bytes  = (size_t)NB * HW * CIN * 2;
    const size_t qkv_bytes = (size_t)NB * HW * CH * 2;
    char* ob = (char*)d_out;
    __hip_bfloat16* xT  = (__hip_bfloat16*)ob;
    __hip_bfloat16* Qt  = (__hip_bfloat16*)(ob + xT_bytes);
    __hip_bfloat16* Kt  = (__hip_bfloat16*)(ob + xT_bytes + qkv_bytes);
    __hip_bfloat16* Vgb = (__hip_bfloat16*)(ob + xT_bytes + 2 * qkv_bytes);
    __hip_bfloat16* PO  = (__hip_bfloat16*)ob;

    char* w = (char*)d_ws;
    __hip_bfloat16* attb = (__hip_bfloat16*)w;                       w += qkv_bytes;
    __hip_bfloat16* WwB  = (__hip_bfloat16*)w;                       w += (size_t)TCH * CIN * 2;
    __hip_bfloat16* ZwB  = (__hip_bfloat16*)w;                       w += (size_t)CIN * CH * 2;
    float* Mbuf = (float*)w;                                         w += (size_t)NSPLIT * NB * HW * 4;
    float* Lbuf = (float*)w;

    cvt_wts<<<dim3(256), 256, 0, stream>>>(Ww, Zw, WwB, ZwB);
    xpose_kernel<<<dim3(HW / 64, CIN / 64, NB), 256, 0, stream>>>(x, xT);
    proj_kernel<<<dim3(HW / 64, TCH / 64, NB), 256, 0, stream>>>(xT, WwB, Wb, Qt, Kt, Vgb);
    attn_kernel<<<dim3((HW + QB - 1) / QB, NB, NSPLIT), 256, 0, stream>>>(Qt, Kt, Vgb,
                                                                          PO, Mbuf, Lbuf);
    merge_kernel<<<dim3(NB * HW * 16 / 256), 256, 0, stream>>>(PO, Mbuf, Lbuf, attb);
    zbn_kernel<<<dim3(HW / 64, CIN / 64, NB), 256, 0, stream>>>(attb, ZwB, gamma, beta,
                                                                mean, var, x, out);
}